// Round 1
// baseline (1543.235 us; speedup 1.0000x reference)
//
#include <hip/hip_runtime.h>
#include <math.h>

// Problem constants (fixed by the reference): B=256, S=2048, I=32, H=128, O=1
#define B_ 256
#define S_ 2048
#define I_ 32
#define H_ 128
#define BPB 2   // batches per block: 16 waves, waves [0,8) -> batch slot 0, [8,16) -> slot 1

// Barrier WITHOUT vmcnt(0) drain (HIP __syncthreads waits vmcnt(0) before
// s_barrier, stalling on in-flight global prefetch/stores every step).
// LDS visibility only needs lgkmcnt(0).
__device__ __forceinline__ void sync_lds() {
    asm volatile("" ::: "memory");
    asm volatile("s_waitcnt lgkmcnt(0)" ::: "memory");
    __builtin_amdgcn_s_barrier();
    asm volatile("" ::: "memory");
}

// tanh(z) = 1 - 2/(e^{2z}+1); exact limits at +-inf, abs err ~1e-7.
__device__ __forceinline__ float fast_tanh(float z) {
    float e = __expf(2.0f * z);
    return 1.0f - 2.0f / (e + 1.0f);
}

template <int CTRL>
__device__ __forceinline__ float dppf(float v) {
    return __int_as_float(__builtin_amdgcn_update_dpp(
        0, __float_as_int(v), CTRL, 0xF, 0xF, false));
}
// DPP controls: 0xB1 = quad_perm [1,0,3,2] (xor1), 0x4E = quad_perm [2,3,0,1]
// (xor2), 0x128 = row_ror:8 (exact xor8 within a 16-lane row).

// Full-wave (64-lane) sum, VALU-only; result valid in lane 63.
__device__ __forceinline__ float dpp_red_sum64(float v) {
    float t;
    t = __int_as_float(__builtin_amdgcn_update_dpp(0, __float_as_int(v), 0x111, 0xf, 0xf, false)); v += t;
    t = __int_as_float(__builtin_amdgcn_update_dpp(0, __float_as_int(v), 0x112, 0xf, 0xf, false)); v += t;
    t = __int_as_float(__builtin_amdgcn_update_dpp(0, __float_as_int(v), 0x114, 0xf, 0xf, false)); v += t;
    t = __int_as_float(__builtin_amdgcn_update_dpp(0, __float_as_int(v), 0x118, 0xf, 0xf, false)); v += t;
    t = __int_as_float(__builtin_amdgcn_update_dpp(0, __float_as_int(v), 0x142, 0xa, 0xf, false)); v += t;
    t = __int_as_float(__builtin_amdgcn_update_dpp(0, __float_as_int(v), 0x143, 0xc, 0xf, false)); v += t;
    return v;
}

#define MAC1(hval, idx)                              \
    a0 = fmaf(hval, WhR[(idx) * 2 + 0], a0);         \
    a1 = fmaf(hval, WhR[(idx) * 2 + 1], a1);
#define MAC4(hv, j)                                  \
    MAC1((hv).x, 4 * (j) + 0)                        \
    MAC1((hv).y, 4 * (j) + 1)                        \
    MAC1((hv).z, 4 * (j) + 2)                        \
    MAC1((hv).w, 4 * (j) + 3)

// One step for one batch-slot. 8 waves per batch, wave-role w owns h in
// [16w,16w+16). Lane: 16k x 2h (32 FMA); k-tree over kg bits {xor1 w/
// h-select, xor2, xor8} pure DPP. xw = x.Wi reduced over the duplicate-lane
// bits (xor2, xor8). Role-waves 4,6 additionally do the lagged score/proj
// full-wave reductions from hn_lds. ONE barrier per step (shared by both
// batch slots - lockstep, but 4 waves/SIMD now interleave the latency
// chains of two independent batches). XA/XB = x register slot (2 x float4,
// row s+2 loaded here; vmcnt-tracked across barriers, never drained).
#define STEP_BODY(s, XA, XB)                                                  \
  {                                                                           \
    const float4* hsrc = (const float4*)&h0_lds[bb][(s) & 1][0];              \
    float4 hv0 = hsrc[kg];                                                    \
    float4 hv1 = hsrc[kg + 8];                                                \
    float4 hv2 = hsrc[kg + 16];                                               \
    float4 hv3 = hsrc[kg + 24];                                               \
    if ((s) > 0) {                                                            \
      if (w == 4) {                                                           \
        float2 hp = *(const float2*)&hn_lds[bb][((s) - 1) & 1][2 * l];        \
        float pv = fmaf(hp.x, waR0, hp.y * waR1);                             \
        pv = dpp_red_sum64(pv);                                               \
        if (l == 63) ((float*)part)[((((s) - 1) << 8) + b) * 2] = pv;         \
      } else if (w == 6) {                                                    \
        float2 hp = *(const float2*)&hn_lds[bb][((s) - 1) & 1][2 * l];        \
        float2 wdp = *(const float2*)&wd_lds[bb][((((s) - 1) & 7) << 7) + 2 * l]; \
        float qv = fmaf(hp.x, wdp.x, hp.y * wdp.y);                           \
        qv = dpp_red_sum64(qv);                                               \
        if (l == 63) ((float*)part)[((((s) - 1) << 8) + b) * 2 + 1] = qv;     \
      }                                                                       \
    }                                                                         \
    float a0 = 0.f, a1 = 0.f;                                                 \
    MAC4(hv0, 0) MAC4(hv1, 1) MAC4(hv2, 2) MAC4(hv3, 3)                       \
    float d0 = dppf<0xB1>(a0), d1 = dppf<0xB1>(a1);                           \
    float acc = (kb0b ? a1 : a0) + (kb0b ? d1 : d0);                          \
    acc += dppf<0x4E>(acc);                                                   \
    acc += dppf<0x128>(acc);                                                  \
    float xwp = biasR;                                                        \
    xwp = fmaf((XA).x, WiC[0], xwp);                                          \
    xwp = fmaf((XA).y, WiC[1], xwp);                                          \
    xwp = fmaf((XA).z, WiC[2], xwp);                                          \
    xwp = fmaf((XA).w, WiC[3], xwp);                                          \
    xwp = fmaf((XB).x, WiC[4], xwp);                                          \
    xwp = fmaf((XB).y, WiC[5], xwp);                                          \
    xwp = fmaf((XB).z, WiC[6], xwp);                                          \
    xwp = fmaf((XB).w, WiC[7], xwp);                                          \
    xwp += dppf<0x4E>(xwp);                                                   \
    xwp += dppf<0x128>(xwp);                                                  \
    float hn = acc + xwp;                                                     \
    {   /* refill slot with x row s+2 (clamped prefetch, in-bounds) */        \
      const float4* xr = (const float4*)xrow;                                 \
      (XA) = xr[0]; (XB) = xr[1];                                             \
      if ((s) <= S_ - 4) xrow += I_;                                          \
    }                                                                         \
    float h0n;                                                                \
    if ((s) == 0)            { hstartR = hn; h0n = 0.0f; }                    \
    else if ((s) == S_ - 2)  { h0n = fast_tanh(hn + hstartR); }               \
    else if (rd == 1)        { h0n = fast_tanh(hn + h0R); }                   \
    else if (cnt == 0)       { h0n = fast_tanh(hn + htR); htR = hn; }         \
    else                     { h0n = fast_tanh(hn); }                         \
    h0R = h0n;                                                                \
    if (wmask) {                                                              \
      h0_lds[bb][((s) + 1) & 1][hf] = h0n;                                    \
      hn_lds[bb][(s) & 1][hf] = hn;                                           \
    }                                                                         \
    cnt = (cnt + 1 == rd) ? 0 : cnt + 1;                                      \
    sync_lds();                                                               \
  }

// 1024 threads = 16 waves = 2 independent batches per block. Previous config
// (512 thr, 1 batch, 2 waves/SIMD) measured 1123 us = ~1300 cy/step with
// VALU issue only ~280 cy/SIMD/step: the wall is exposed serial latency
// (post-barrier LDS broadcast burst + 16-deep FMA chain + DPP trees + tanh
// + the waves-4/6 straggler reduction), paid once per batch-step. Running
// TWO batches lockstep in one block (4 waves/SIMD) amortizes that serial
// overhead over 2 batch-steps: batch A's stall cycles are filled by batch
// B's issue. Weight registers (WhR/WiC) are shared values, identical code.
// waves_per_eu(4,4) caps the allocator at 128 VGPR/wave; static demand ~90.
__global__ __launch_bounds__(1024)
__attribute__((amdgpu_waves_per_eu(4, 4)))
void rnn_kernel(
    const float* __restrict__ x, const float* __restrict__ Wi,
    const float* __restrict__ bi, const float* __restrict__ Wh,
    const float* __restrict__ bh, const float* __restrict__ Wa,
    const float* __restrict__ Wd, const int* __restrict__ rdp,
    float2* __restrict__ part)
{
    const int t = threadIdx.x;
    const int w16 = t >> 6;          // wave id 0..15
    const int bb = w16 >> 3;         // batch slot 0/1
    const int w = w16 & 7;           // wave ROLE 0..7 (same as 1-batch kernel)
    const int b = blockIdx.x * BPB + bb;   // global batch
    const int l = t & 63;
    // k-group bits {0,1,3}; h-group bits {2,4,5}; duplicate-lane bits {1,3}
    const int  kg    = (l & 3) | (((l >> 3) & 1) << 2);              // 0..7
    const int  hg    = ((l >> 2) & 1) | (((l >> 4) & 1) << 1)
                     | (((l >> 5) & 1) << 2);                        // 0..7
    const int  hbase = 16 * w + 2 * hg;
    const int  hf    = hbase + (l & 1);     // this lane's final h
    const bool kb0b  = (l & 1);
    const bool wmask = ((l & 0xA) == 0);    // 16 writer lanes (distinct h)
    const int  i0x   = 8 * (((l >> 1) & 1) | (((l >> 3) & 1) << 1)); // 0,8,16,24

    __shared__ __align__(16) float h0_lds[BPB][2][H_];
    __shared__ __align__(16) float hn_lds[BPB][2][H_];
    __shared__ __align__(16) float wd_lds[BPB][8 * H_];

    const int rd = rdp[0];
    // Wd slices for both batches of this block (8*H per batch)
    for (int j = t; j < BPB * 8 * H_; j += 1024) {
        int bbj = j >> 10;            // 8*H_ == 1024
        int jj  = j & 1023;
        wd_lds[bbj][jj] =
            Wd[((jj >> 7) << 15) + ((blockIdx.x * BPB + bbj) << 7) + (jj & 127)];
    }
    if (t < BPB * H_) h0_lds[t >> 7][0][t & 127] = 0.0f;

    // Wh: lane's 16 k (k = 4kg + 32j + c) x 2 h (hbase, hbase+1) - shared
    // weights, identical per batch slot.
    float WhR[32];
#pragma unroll
    for (int j = 0; j < 4; ++j)
#pragma unroll
        for (int c = 0; c < 4; ++c) {
            int k = 4 * kg + 32 * j + c;
            float2 wv = *(const float2*)(Wh + (size_t)k * H_ + hbase);
            WhR[(4 * j + c) * 2 + 0] = wv.x;
            WhR[(4 * j + c) * 2 + 1] = wv.y;
        }
    // Wi: this lane's i-slice (8 of 32) for its h
    float WiC[8];
#pragma unroll
    for (int i = 0; i < 8; ++i) WiC[i] = Wi[(size_t)(i0x + i) * H_ + hf];
    const float biasR = wmask ? (bi[hf] + bh[hf]) : 0.0f;  // added once per h
    const float waR0 = Wa[2 * l], waR1 = Wa[2 * l + 1];    // used by role-wave 4

    // x register pipeline: slot0 = row s (even s), slot1 = row s (odd s)
    const float* xrow = x + (size_t)b * S_ * I_ + i0x;
    float4 xA0 = ((const float4*)xrow)[0];
    float4 xB0 = ((const float4*)xrow)[1];
    float4 xA1 = ((const float4*)(xrow + I_))[0];
    float4 xB1 = ((const float4*)(xrow + I_))[1];
    xrow += 2 * I_;   // -> row 2 (next prefetch target)

    sync_lds();

    float htR = 0.f, hstartR = 0.f, h0R = 0.f;
    int cnt = 0;  // s % rd, incremental

    for (int s = 0; s < S_; s += 2) {
        STEP_BODY(s, xA0, xB0)
        STEP_BODY(s + 1, xA1, xB1)
    }

    // epilogue: score/proj for s = S-1 (lagged by one step)
    if (w == 4) {
        float2 hp = *(const float2*)&hn_lds[bb][(S_ - 1) & 1][2 * l];
        float pv = fmaf(hp.x, waR0, hp.y * waR1);
        pv = dpp_red_sum64(pv);
        if (l == 63) ((float*)part)[(((S_ - 1) << 8) + b) * 2] = pv;
    } else if (w == 6) {
        float2 hp = *(const float2*)&hn_lds[bb][(S_ - 1) & 1][2 * l];
        float2 wdp = *(const float2*)&wd_lds[bb][(((S_ - 1) & 7) << 7) + 2 * l];
        float qv = fmaf(hp.x, wdp.x, hp.y * wdp.y);
        qv = dpp_red_sum64(qv);
        if (l == 63) ((float*)part)[(((S_ - 1) << 8) + b) * 2 + 1] = qv;
    }
}

// out[r] = bd + sum_{f in chunk r} softmax(score)_f * d_f, chunk = 2048 flat
// (s,b) pairs with s in [8r,8r+8). ba is softmax-invariant -> omitted.
__global__ __launch_bounds__(256) void attn_kernel(
    const float2* __restrict__ part, const float* __restrict__ bd,
    float* __restrict__ out)
{
    const int r = blockIdx.x;
    const int t = threadIdx.x;
    float sc[8], dv[8];
    float mx = -1e30f;
#pragma unroll
    for (int u = 0; u < 8; ++u) {
        int f = (r << 11) + (u << 8) + t;
        float2 a = part[f];
        sc[u] = a.x;
        dv[u] = a.y;
        mx = fmaxf(mx, sc[u]);
    }
    __shared__ float redm[4], redz[4], redw[4];
#pragma unroll
    for (int off = 32; off > 0; off >>= 1) mx = fmaxf(mx, __shfl_xor(mx, off, 64));
    if ((t & 63) == 0) redm[t >> 6] = mx;
    __syncthreads();
    mx = fmaxf(fmaxf(redm[0], redm[1]), fmaxf(redm[2], redm[3]));
    float z = 0.f, wv = 0.f;
#pragma unroll
    for (int u = 0; u < 8; ++u) {
        float e = __expf(sc[u] - mx);
        z += e;
        wv += e * dv[u];
    }
#pragma unroll
    for (int off = 32; off > 0; off >>= 1) {
        z += __shfl_xor(z, off, 64);
        wv += __shfl_xor(wv, off, 64);
    }
    if ((t & 63) == 0) { redz[t >> 6] = z; redw[t >> 6] = wv; }
    __syncthreads();
    if (t == 0) {
        float Z = redz[0] + redz[1] + redz[2] + redz[3];
        float W = redw[0] + redw[1] + redw[2] + redw[3];
        out[r] = bd[0] + W / Z;
    }
}

extern "C" void kernel_launch(void* const* d_in, const int* in_sizes, int n_in,
                              void* d_out, int out_size, void* d_ws, size_t ws_size,
                              hipStream_t stream) {
    const float* x  = (const float*)d_in[0];
    const float* Wi = (const float*)d_in[1];
    const float* bi = (const float*)d_in[2];
    const float* Wh = (const float*)d_in[3];
    const float* bh = (const float*)d_in[4];
    const float* Wa = (const float*)d_in[5];
    // d_in[6] = ba: constant shift inside each softmax chunk -> no effect.
    const float* Wd = (const float*)d_in[7];
    const float* bd = (const float*)d_in[8];
    const int*  rdp = (const int*)d_in[9];

    // Workspace: one (S*B) float2 array of combined {score, d} (4 MiB)
    float2* part = (float2*)d_ws;

    rnn_kernel<<<B_ / BPB, 1024, 0, stream>>>(x, Wi, bi, Wh, bh, Wa, Wd, rdp, part);
    attn_kernel<<<B_, 256, 0, stream>>>(part, bd, (float*)d_out);
}

// Round 2
// 1101.248 us; speedup vs baseline: 1.4014x; 1.4014x over previous
//
#include <hip/hip_runtime.h>
#include <math.h>

// Problem constants (fixed by the reference): B=256, S=2048, I=32, H=128, O=1
#define B_ 256
#define S_ 2048
#define I_ 32
#define H_ 128

// Barrier WITHOUT vmcnt(0) drain (HIP __syncthreads waits vmcnt(0) before
// s_barrier, stalling on in-flight global prefetch/stores every step).
// LDS visibility only needs lgkmcnt(0).
__device__ __forceinline__ void sync_lds() {
    asm volatile("" ::: "memory");
    asm volatile("s_waitcnt lgkmcnt(0)" ::: "memory");
    __builtin_amdgcn_s_barrier();
    asm volatile("" ::: "memory");
}

// tanh(z) = 1 - 2/(e^{2z}+1); exact limits at +-inf, abs err ~1e-7.
__device__ __forceinline__ float fast_tanh(float z) {
    float e = __expf(2.0f * z);
    return 1.0f - 2.0f / (e + 1.0f);
}

template <int CTRL>
__device__ __forceinline__ float dppf(float v) {
    return __int_as_float(__builtin_amdgcn_update_dpp(
        0, __float_as_int(v), CTRL, 0xF, 0xF, false));
}
// DPP controls: 0xB1 = quad_perm [1,0,3,2] (xor1), 0x4E = quad_perm [2,3,0,1]
// (xor2), 0x124 = row_ror:4, 0x128 = row_ror:8 (exact xor8 within a 16-row).

// Full-wave (64-lane) sum, VALU-only; result valid in lane 63.
__device__ __forceinline__ float dpp_red_sum64(float v) {
    float t;
    t = __int_as_float(__builtin_amdgcn_update_dpp(0, __float_as_int(v), 0x111, 0xf, 0xf, false)); v += t;
    t = __int_as_float(__builtin_amdgcn_update_dpp(0, __float_as_int(v), 0x112, 0xf, 0xf, false)); v += t;
    t = __int_as_float(__builtin_amdgcn_update_dpp(0, __float_as_int(v), 0x114, 0xf, 0xf, false)); v += t;
    t = __int_as_float(__builtin_amdgcn_update_dpp(0, __float_as_int(v), 0x118, 0xf, 0xf, false)); v += t;
    t = __int_as_float(__builtin_amdgcn_update_dpp(0, __float_as_int(v), 0x142, 0xa, 0xf, false)); v += t;
    t = __int_as_float(__builtin_amdgcn_update_dpp(0, __float_as_int(v), 0x143, 0xc, 0xf, false)); v += t;
    return v;
}

#define MAC1(hval, idx)                              \
    a0 = fmaf(hval, WhR[(idx) * 2 + 0], a0);         \
    a1 = fmaf(hval, WhR[(idx) * 2 + 1], a1);
#define MAC4(hv, j)                                  \
    MAC1((hv).x, 4 * (j) + 0)                        \
    MAC1((hv).y, 4 * (j) + 1)                        \
    MAC1((hv).z, 4 * (j) + 2)                        \
    MAC1((hv).w, 4 * (j) + 3)

// One step. 8 symmetric waves, wave w owns h in [16w,16w+16). Lane: 16k x 2h
// (32 FMA); k-tree: xor1 (h-select) then SHARED xor2+xor8 tail that also
// reduces xwp's duplicate-lane bits (merged trees: xwp added after level 1).
// Score/proj: every wave computes its own slice's partial IN-REGISTER from hn
// (wa/wd preloaded, x0.25 for the 4-fold lane duplication), dpp_red_sum64,
// lane 63 -> pl_lds[pw][w]; wave 0 combines 8 partials with a 3-level DPP
// tree at lag 2 and stores part[] as one dwordx2. No hn_lds, no wd_lds, no
// straggler waves -> balanced arrival at the single per-step barrier.
// WDQ = this phase's (s&7) Wd coefficient register (loop unrolled x8 so the
// selection is static -- no dynamic indexing / scratch).
#define STEP_BODY(s, XA, XB, WDQ)                                             \
  {                                                                           \
    const float4* hsrc = (const float4*)&h0_lds[(s) & 1][0];                  \
    float4 hv0 = hsrc[kg];                                                    \
    float4 hv1 = hsrc[kg + 8];                                                \
    float4 hv2 = hsrc[kg + 16];                                               \
    float4 hv3 = hsrc[kg + 24];                                               \
    if (w == 0 && (s) >= 2) {  /* combine partials of step s-2 */             \
      int pr = (pw == 2) ? 0 : pw + 1;  /* (s-2)%3 == (pw+1)%3 */             \
      float2 pp = pl_lds[pr][l & 7];                                          \
      float px = pp.x, py = pp.y;                                             \
      px += dppf<0xB1>(px);  py += dppf<0xB1>(py);                            \
      px += dppf<0x4E>(px);  py += dppf<0x4E>(py);                            \
      px += dppf<0x124>(px); py += dppf<0x124>(py);                           \
      if (l == 0) part[(((s) - 2) << 8) + b] = make_float2(px, py);           \
    }                                                                         \
    float a0 = 0.f, a1 = 0.f;                                                 \
    MAC4(hv0, 0) MAC4(hv1, 1) MAC4(hv2, 2) MAC4(hv3, 3)                       \
    float d0 = dppf<0xB1>(a0), d1 = dppf<0xB1>(a1);                           \
    float t = (kb0b ? a1 : a0) + (kb0b ? d1 : d0);                            \
    float xwp = biasR;                                                        \
    xwp = fmaf((XA).x, WiC[0], xwp);                                          \
    xwp = fmaf((XA).y, WiC[1], xwp);                                          \
    xwp = fmaf((XA).z, WiC[2], xwp);                                          \
    xwp = fmaf((XA).w, WiC[3], xwp);                                          \
    xwp = fmaf((XB).x, WiC[4], xwp);                                          \
    xwp = fmaf((XB).y, WiC[5], xwp);                                          \
    xwp = fmaf((XB).z, WiC[6], xwp);                                          \
    xwp = fmaf((XB).w, WiC[7], xwp);                                          \
    t += xwp;                       /* merged: shared dup-bit tail */         \
    t += dppf<0x4E>(t);                                                       \
    t += dppf<0x128>(t);                                                      \
    float hn = t;                                                             \
    {   /* refill slot with x row s+2 (clamped prefetch, in-bounds) */        \
      const float4* xr = (const float4*)xrow;                                 \
      (XA) = xr[0]; (XB) = xr[1];                                             \
      if ((s) <= S_ - 4) xrow += I_;                                          \
    }                                                                         \
    {   /* balanced score/proj partial for this wave's 16 h */                \
      float pv = hn * waq;                                                    \
      float qv = hn * (WDQ);                                                  \
      pv = dpp_red_sum64(pv);                                                 \
      qv = dpp_red_sum64(qv);                                                 \
      if (l == 63) pl_lds[pw][w] = make_float2(pv, qv);                       \
    }                                                                         \
    float h0n;                                                                \
    if ((s) == 0)            { hstartR = hn; h0n = 0.0f; }                    \
    else if ((s) == S_ - 2)  { h0n = fast_tanh(hn + hstartR); }               \
    else if (rd == 1)        { h0n = fast_tanh(hn + h0R); }                   \
    else if (cnt == 0)       { h0n = fast_tanh(hn + htR); htR = hn; }         \
    else                     { h0n = fast_tanh(hn); }                         \
    h0R = h0n;                                                                \
    if (wmask) h0_lds[((s) + 1) & 1][hf] = h0n;                               \
    cnt = (cnt + 1 == rd) ? 0 : cnt + 1;                                      \
    pw = (pw == 2) ? 0 : pw + 1;                                              \
    sync_lds();                                                               \
  }

// 512 threads = 8 waves per batch, 1 batch per block, 256 blocks = all CUs.
// Round-1 lesson (measured): the per-step wall is ADDITIVE -- per-SIMD VALU
// issue + per-CU LDS pipe burst + dep chains + barrier skew all serialize at
// the lockstep barrier (2 batches/block reproduced the additive prediction
// 740ns/step exactly). So we shrink the sum: straggler reductions removed
// (balanced per-wave partials), hn_lds/wd_lds deleted, reduction trees
// merged. waves_per_eu(2,2) caps allocator at 256 VGPR; static demand ~110.
__global__ __launch_bounds__(512)
__attribute__((amdgpu_waves_per_eu(2, 2)))
void rnn_kernel(
    const float* __restrict__ x, const float* __restrict__ Wi,
    const float* __restrict__ bi, const float* __restrict__ Wh,
    const float* __restrict__ bh, const float* __restrict__ Wa,
    const float* __restrict__ Wd, const int* __restrict__ rdp,
    float2* __restrict__ part)
{
    const int b = blockIdx.x;
    const int t = threadIdx.x;
    const int w = t >> 6;           // wave id 0..7
    const int l = t & 63;
    // k-group bits {0,1,3}; h-group bits {2,4,5}; duplicate-lane bits {1,3}
    const int  kg    = (l & 3) | (((l >> 3) & 1) << 2);              // 0..7
    const int  hg    = ((l >> 2) & 1) | (((l >> 4) & 1) << 1)
                     | (((l >> 5) & 1) << 2);                        // 0..7
    const int  hbase = 16 * w + 2 * hg;
    const int  hf    = hbase + (l & 1);     // this lane's final h
    const bool kb0b  = (l & 1);
    const bool wmask = ((l & 0xA) == 0);    // 16 writer lanes (distinct h)
    const int  i0x   = 8 * (((l >> 1) & 1) | (((l >> 3) & 1) << 1)); // 0,8,16,24

    __shared__ __align__(16) float h0_lds[2][H_];
    __shared__ __align__(8)  float2 pl_lds[3][8];   // 3-deep partial ring

    const int rd = rdp[0];
    if (t < H_) h0_lds[0][t] = 0.0f;

    // Wh: lane's 16 k (k = 4kg + 32j + c) x 2 h (hbase, hbase+1)
    float WhR[32];
#pragma unroll
    for (int j = 0; j < 4; ++j)
#pragma unroll
        for (int c = 0; c < 4; ++c) {
            int k = 4 * kg + 32 * j + c;
            float2 wv = *(const float2*)(Wh + (size_t)k * H_ + hbase);
            WhR[(4 * j + c) * 2 + 0] = wv.x;
            WhR[(4 * j + c) * 2 + 1] = wv.y;
        }
    // Wi: this lane's i-slice (8 of 32) for its h
    float WiC[8];
#pragma unroll
    for (int i = 0; i < 8; ++i) WiC[i] = Wi[(size_t)(i0x + i) * H_ + hf];
    const float biasR = wmask ? (bi[hf] + bh[hf]) : 0.0f;  // added once per h

    // score/proj coefficients for this lane's h; x0.25 folds away the 4-fold
    // lane duplication in the full-wave sum (duplicates are bitwise equal).
    const float waq = Wa[hf] * 0.25f;
    const float wdq0 = Wd[(0 << 15) + (b << 7) + hf] * 0.25f;
    const float wdq1 = Wd[(1 << 15) + (b << 7) + hf] * 0.25f;
    const float wdq2 = Wd[(2 << 15) + (b << 7) + hf] * 0.25f;
    const float wdq3 = Wd[(3 << 15) + (b << 7) + hf] * 0.25f;
    const float wdq4 = Wd[(4 << 15) + (b << 7) + hf] * 0.25f;
    const float wdq5 = Wd[(5 << 15) + (b << 7) + hf] * 0.25f;
    const float wdq6 = Wd[(6 << 15) + (b << 7) + hf] * 0.25f;
    const float wdq7 = Wd[(7 << 15) + (b << 7) + hf] * 0.25f;

    // x register pipeline: slot0 = row s (even s), slot1 = row s (odd s)
    const float* xrow = x + (size_t)b * S_ * I_ + i0x;
    float4 xA0 = ((const float4*)xrow)[0];
    float4 xB0 = ((const float4*)xrow)[1];
    float4 xA1 = ((const float4*)(xrow + I_))[0];
    float4 xB1 = ((const float4*)(xrow + I_))[1];
    xrow += 2 * I_;   // -> row 2 (next prefetch target)

    sync_lds();

    float htR = 0.f, hstartR = 0.f, h0R = 0.f;
    int cnt = 0;  // s % rd, incremental
    int pw  = 0;  // s % 3, incremental (partial ring index)

    for (int s = 0; s < S_; s += 8) {
        STEP_BODY(s,     xA0, xB0, wdq0)
        STEP_BODY(s + 1, xA1, xB1, wdq1)
        STEP_BODY(s + 2, xA0, xB0, wdq2)
        STEP_BODY(s + 3, xA1, xB1, wdq3)
        STEP_BODY(s + 4, xA0, xB0, wdq4)
        STEP_BODY(s + 5, xA1, xB1, wdq5)
        STEP_BODY(s + 6, xA0, xB0, wdq6)
        STEP_BODY(s + 7, xA1, xB1, wdq7)
    }

    // epilogue: combine partials for s = S-2 (ring 0) and s = S-1 (ring 1)
    if (w == 0) {
#pragma unroll
        for (int e = 0; e < 2; ++e) {
            float2 pp = pl_lds[e][l & 7];   // (S-2)%3==0, (S-1)%3==1
            float px = pp.x, py = pp.y;
            px += dppf<0xB1>(px);  py += dppf<0xB1>(py);
            px += dppf<0x4E>(px);  py += dppf<0x4E>(py);
            px += dppf<0x124>(px); py += dppf<0x124>(py);
            if (l == 0) part[((S_ - 2 + e) << 8) + b] = make_float2(px, py);
        }
    }
}

// out[r] = bd + sum_{f in chunk r} softmax(score)_f * d_f, chunk = 2048 flat
// (s,b) pairs with s in [8r,8r+8). ba is softmax-invariant -> omitted.
__global__ __launch_bounds__(256) void attn_kernel(
    const float2* __restrict__ part, const float* __restrict__ bd,
    float* __restrict__ out)
{
    const int r = blockIdx.x;
    const int t = threadIdx.x;
    float sc[8], dv[8];
    float mx = -1e30f;
#pragma unroll
    for (int u = 0; u < 8; ++u) {
        int f = (r << 11) + (u << 8) + t;
        float2 a = part[f];
        sc[u] = a.x;
        dv[u] = a.y;
        mx = fmaxf(mx, sc[u]);
    }
    __shared__ float redm[4], redz[4], redw[4];
#pragma unroll
    for (int off = 32; off > 0; off >>= 1) mx = fmaxf(mx, __shfl_xor(mx, off, 64));
    if ((t & 63) == 0) redm[t >> 6] = mx;
    __syncthreads();
    mx = fmaxf(fmaxf(redm[0], redm[1]), fmaxf(redm[2], redm[3]));
    float z = 0.f, wv = 0.f;
#pragma unroll
    for (int u = 0; u < 8; ++u) {
        float e = __expf(sc[u] - mx);
        z += e;
        wv += e * dv[u];
    }
#pragma unroll
    for (int off = 32; off > 0; off >>= 1) {
        z += __shfl_xor(z, off, 64);
        wv += __shfl_xor(wv, off, 64);
    }
    if ((t & 63) == 0) { redz[t >> 6] = z; redw[t >> 6] = wv; }
    __syncthreads();
    if (t == 0) {
        float Z = redz[0] + redz[1] + redz[2] + redz[3];
        float W = redw[0] + redw[1] + redw[2] + redw[3];
        out[r] = bd[0] + W / Z;
    }
}

extern "C" void kernel_launch(void* const* d_in, const int* in_sizes, int n_in,
                              void* d_out, int out_size, void* d_ws, size_t ws_size,
                              hipStream_t stream) {
    const float* x  = (const float*)d_in[0];
    const float* Wi = (const float*)d_in[1];
    const float* bi = (const float*)d_in[2];
    const float* Wh = (const float*)d_in[3];
    const float* bh = (const float*)d_in[4];
    const float* Wa = (const float*)d_in[5];
    // d_in[6] = ba: constant shift inside each softmax chunk -> no effect.
    const float* Wd = (const float*)d_in[7];
    const float* bd = (const float*)d_in[8];
    const int*  rdp = (const int*)d_in[9];

    // Workspace: one (S*B) float2 array of combined {score, d} (4 MiB)
    float2* part = (float2*)d_ws;

    rnn_kernel<<<B_, 512, 0, stream>>>(x, Wi, bi, Wh, bh, Wa, Wd, rdp, part);
    attn_kernel<<<B_, 256, 0, stream>>>(part, bd, (float*)d_out);
}

// Round 3
// 1034.589 us; speedup vs baseline: 1.4916x; 1.0644x over previous
//
#include <hip/hip_runtime.h>
#include <math.h>

// Problem constants (fixed by the reference): B=256, S=2048, I=32, H=128, O=1
#define B_ 256
#define S_ 2048
#define I_ 32
#define H_ 128

// Barrier WITHOUT vmcnt(0) drain (HIP __syncthreads waits vmcnt(0) before
// s_barrier, stalling on in-flight global prefetch/stores every step).
// LDS visibility only needs lgkmcnt(0).
__device__ __forceinline__ void sync_lds() {
    asm volatile("" ::: "memory");
    asm volatile("s_waitcnt lgkmcnt(0)" ::: "memory");
    __builtin_amdgcn_s_barrier();
    asm volatile("" ::: "memory");
}

// tanh(z) = 1 - 2/(e^{2z}+1); exact limits at +-inf, abs err ~1e-7.
__device__ __forceinline__ float fast_tanh(float z) {
    float e = __expf(2.0f * z);
    return 1.0f - 2.0f / (e + 1.0f);
}

template <int CTRL>
__device__ __forceinline__ float dppf(float v) {
    return __int_as_float(__builtin_amdgcn_update_dpp(
        0, __float_as_int(v), CTRL, 0xF, 0xF, false));
}
// DPP controls: 0xB1 = quad_perm [1,0,3,2] (xor1), 0x4E = quad_perm [2,3,0,1]
// (xor2), 0x124 = row_ror:4 (= b2-flip given b3-duplicates), 0x128 =
// row_ror:8 (exact xor8 within a 16-lane row).

// LDS-pipe lane exchanges (full-wave): xor16 via ds_swizzle BitMode,
// xor32 via ds_bpermute (crossbar, no LDS storage touched).
__device__ __forceinline__ float swz_xor16(float v) {
    return __int_as_float(__builtin_amdgcn_ds_swizzle(__float_as_int(v), 0x401F));
}
__device__ __forceinline__ float bperm_f(int addr_bytes, float v) {
    return __int_as_float(__builtin_amdgcn_ds_bpermute(addr_bytes, __float_as_int(v)));
}

#define MAC1(hval, idx)                              \
    a0 = fmaf(hval, WhR[(idx) * 2 + 0], a0);         \
    a1 = fmaf(hval, WhR[(idx) * 2 + 1], a1);
#define MAC4(hv, j)                                  \
    MAC1((hv).x, 4 * (j) + 0)                        \
    MAC1((hv).y, 4 * (j) + 1)                        \
    MAC1((hv).z, 4 * (j) + 2)                        \
    MAC1((hv).w, 4 * (j) + 3)

// One step, s = (g)*8 + PH (PH compile-time -> all &1/&3 ring indices fold).
// 8 symmetric waves, wave w owns h in [16w,16w+16). Lane: 16k x 2h (32 FMA);
// k-tree: xor1 per-acc, select, then SHARED xor2+xor8 tail that also reduces
// xwp's duplicate-lane bits.
// Score/proj (DEFERRED 1 step, off the pre-barrier critical path):
//   uP = hn * c[PH] where lane-role bit b1 selects c = Wa[hf] (pv) or
//   Wd[(s&7)<<15 + b<<7 + hf] (qv). At the TOP of the next step, a
//   class-preserving reduce over h-bits {0,2,4,5} -- dpp xor1, dpp ror:4
//   (exact b2-flip via b3-duplicates), swizzle xor16, bpermute xor32 --
//   yields per-class totals; lanes 0 (pv) and 2 (qv) write one float each
//   into pl_lds ring (s-1)&3. Wave 0 combines the 8 wave-partials of step
//   s-2 with the proven 3-level DPP tree and stores part[] (dwordx2).
// x refill: group-hoisted pointer + immediate offsets ((PH+2)*I_); the two
// dead tail loads (s >= S_-2) are skipped, so no clamping arithmetic.
#define STEP_BODY(g, PH, XA, XB, CPH)                                         \
  {                                                                           \
    const int s_ = (g) * 8 + (PH);                                            \
    const float4* hsrc = (const float4*)&h0_lds[(PH) & 1][0];                 \
    float4 hv0 = hsrc[kg];                                                    \
    float4 hv1 = hsrc[kg + 8];                                                \
    float4 hv2 = hsrc[kg + 16];                                               \
    float4 hv3 = hsrc[kg + 24];                                               \
    if (s_ >= 1) {   /* deferred score/proj reduce of step s-1 */             \
      float r = uP;                                                           \
      r += dppf<0xB1>(r);                                                     \
      r += dppf<0x124>(r);                                                    \
      r += swz_xor16(r);                                                      \
      r += bperm_f(bp32, r);                                                  \
      if ((l & 0x3D) == 0)                                                    \
        ((float*)&pl_lds[(unsigned)(s_ - 1) & 3][w])[(l >> 1) & 1] = r;       \
    }                                                                         \
    if (w == 0 && s_ >= 2) {  /* combine partials of step s-2 */              \
      float2 pp = pl_lds[(unsigned)(s_ - 2) & 3][l & 7];                      \
      float px = pp.x, py = pp.y;                                             \
      px += dppf<0xB1>(px);  py += dppf<0xB1>(py);                            \
      px += dppf<0x4E>(px);  py += dppf<0x4E>(py);                            \
      px += dppf<0x124>(px); py += dppf<0x124>(py);                           \
      if (l == 0) part[((s_ - 2) << 8) + b] = make_float2(px, py);            \
    }                                                                         \
    float a0 = 0.f, a1 = 0.f;                                                 \
    MAC4(hv0, 0) MAC4(hv1, 1) MAC4(hv2, 2) MAC4(hv3, 3)                       \
    a0 += dppf<0xB1>(a0);                                                     \
    a1 += dppf<0xB1>(a1);                                                     \
    float t = kb0b ? a1 : a0;                                                 \
    float xwp = biasR;                                                        \
    xwp = fmaf((XA).x, WiC[0], xwp);                                          \
    xwp = fmaf((XA).y, WiC[1], xwp);                                          \
    xwp = fmaf((XA).z, WiC[2], xwp);                                          \
    xwp = fmaf((XA).w, WiC[3], xwp);                                          \
    xwp = fmaf((XB).x, WiC[4], xwp);                                          \
    xwp = fmaf((XB).y, WiC[5], xwp);                                          \
    xwp = fmaf((XB).z, WiC[6], xwp);                                          \
    xwp = fmaf((XB).w, WiC[7], xwp);                                          \
    t += xwp;                       /* merged: shared dup-bit tail */         \
    t += dppf<0x4E>(t);                                                       \
    t += dppf<0x128>(t);                                                      \
    float hn = t;                                                             \
    if (s_ < S_ - 2) {  /* refill slot with x row s+2 (imm offset) */         \
      const float4* xr = (const float4*)(xgrp + ((PH) + 2) * I_);             \
      (XA) = xr[0]; (XB) = xr[1];                                             \
    }                                                                         \
    uP = hn * (CPH);                /* reduced at top of next step */         \
    float h0n;                                                                \
    if (s_ == 0)            { hstartR = hn; h0n = 0.0f; }                     \
    else if (s_ == S_ - 2)  { h0n = fast_tanh(hn + hstartR); }                \
    else if (rd == 1)       { h0n = fast_tanh(hn + h0R); }                    \
    else if (cnt == 0)      { h0n = fast_tanh(hn + htR); htR = hn; }          \
    else                    { h0n = fast_tanh(hn); }                          \
    h0R = h0n;                                                                \
    if (wmask) h0_lds[((PH) + 1) & 1][hf] = h0n;                              \
    cnt = (cnt + 1 == rd) ? 0 : cnt + 1;                                      \
    sync_lds();                                                               \
  }

// 512 threads = 8 waves per batch, 1 batch per block, 256 blocks = all CUs.
// Model (rounds 1-2, measured): per-SIMD VALU issue is NOT binding (round 2
// added ~100 VALU/CU/step and the wall DROPPED); wall ~= post-barrier LDS
// burst + serial dep chains + barrier skew, with VALU partially overlapped.
// This round makes the score/proj path ~3x cheaper and defers it off the
// pre-barrier critical path. waves_per_eu(2,2): 2 waves/SIMD, VGPR ~90.
__global__ __launch_bounds__(512)
__attribute__((amdgpu_waves_per_eu(2, 2)))
void rnn_kernel(
    const float* __restrict__ x, const float* __restrict__ Wi,
    const float* __restrict__ bi, const float* __restrict__ Wh,
    const float* __restrict__ bh, const float* __restrict__ Wa,
    const float* __restrict__ Wd, const int* __restrict__ rdp,
    float2* __restrict__ part)
{
    const int b = blockIdx.x;
    const int t = threadIdx.x;
    const int w = t >> 6;           // wave id 0..7
    const int l = t & 63;
    // k-group bits {0,1,3}; h-group bits {2,4,5}; duplicate-lane bits {1,3}
    const int  kg    = (l & 3) | (((l >> 3) & 1) << 2);              // 0..7
    const int  hg    = ((l >> 2) & 1) | (((l >> 4) & 1) << 1)
                     | (((l >> 5) & 1) << 2);                        // 0..7
    const int  hbase = 16 * w + 2 * hg;
    const int  hf    = hbase + (l & 1);     // this lane's final h
    const bool kb0b  = (l & 1);
    const bool wmask = ((l & 0xA) == 0);    // 16 writer lanes (distinct h)
    const int  i0x   = 8 * (((l >> 1) & 1) | (((l >> 3) & 1) << 1)); // 0,8,16,24
    const int  bp32  = (l ^ 32) << 2;       // bpermute byte addr for xor32

    __shared__ __align__(16) float h0_lds[2][H_];
    __shared__ __align__(8)  float2 pl_lds[4][8];   // 4-deep partial ring

    const int rd = rdp[0];
    if (t < H_) h0_lds[0][t] = 0.0f;

    // Wh: lane's 16 k (k = 4kg + 32j + c) x 2 h (hbase, hbase+1)
    float WhR[32];
#pragma unroll
    for (int j = 0; j < 4; ++j)
#pragma unroll
        for (int c = 0; c < 4; ++c) {
            int k = 4 * kg + 32 * j + c;
            float2 wv = *(const float2*)(Wh + (size_t)k * H_ + hbase);
            WhR[(4 * j + c) * 2 + 0] = wv.x;
            WhR[(4 * j + c) * 2 + 1] = wv.y;
        }
    // Wi: this lane's i-slice (8 of 32) for its h
    float WiC[8];
#pragma unroll
    for (int i = 0; i < 8; ++i) WiC[i] = Wi[(size_t)(i0x + i) * H_ + hf];
    const float biasR = wmask ? (bi[hf] + bh[hf]) : 0.0f;  // added once per h

    // Per-phase score/proj coefficient: lane-role bit b1 selects pv (Wa) or
    // qv (Wd column for this b, phase s&7). The class-preserving reduction
    // counts each h exactly once per class -> NO duplication scale factor.
    const bool clsq = (l >> 1) & 1;   // b1: 0 = pv lane, 1 = qv lane
    const float waC = Wa[hf];
    float cph[8];
#pragma unroll
    for (int K = 0; K < 8; ++K)
        cph[K] = clsq ? Wd[(K << 15) + (b << 7) + hf] : waC;

    // x group pointer: rows of this group reachable via imm offsets
    const float* xgrp = x + (size_t)b * (S_ * I_) + i0x;
    float4 xA0 = ((const float4*)xgrp)[0];
    float4 xB0 = ((const float4*)xgrp)[1];
    float4 xA1 = ((const float4*)(xgrp + I_))[0];
    float4 xB1 = ((const float4*)(xgrp + I_))[1];

    sync_lds();

    float htR = 0.f, hstartR = 0.f, h0R = 0.f;
    float uP = 0.f;   // previous step's (hn * coef), reduced next step
    int cnt = 0;      // s % rd, incremental

    for (int g = 0; g < S_ / 8; ++g) {
        STEP_BODY(g, 0, xA0, xB0, cph[0])
        STEP_BODY(g, 1, xA1, xB1, cph[1])
        STEP_BODY(g, 2, xA0, xB0, cph[2])
        STEP_BODY(g, 3, xA1, xB1, cph[3])
        STEP_BODY(g, 4, xA0, xB0, cph[4])
        STEP_BODY(g, 5, xA1, xB1, cph[5])
        STEP_BODY(g, 6, xA0, xB0, cph[6])
        STEP_BODY(g, 7, xA1, xB1, cph[7])
        xgrp += 8 * I_;
    }

    // epilogue: reduce s = S-1's partial (ring 3), then wave 0 combines
    // rings 2 (s = S-2, written at top of step S-1) and 3.
    {
        float r = uP;
        r += dppf<0xB1>(r);
        r += dppf<0x124>(r);
        r += swz_xor16(r);
        r += bperm_f(bp32, r);
        if ((l & 0x3D) == 0)
            ((float*)&pl_lds[3][w])[(l >> 1) & 1] = r;
    }
    sync_lds();
    if (w == 0) {
#pragma unroll
        for (int e = 0; e < 2; ++e) {
            float2 pp = pl_lds[2 + e][l & 7];
            float px = pp.x, py = pp.y;
            px += dppf<0xB1>(px);  py += dppf<0xB1>(py);
            px += dppf<0x4E>(px);  py += dppf<0x4E>(py);
            px += dppf<0x124>(px); py += dppf<0x124>(py);
            if (l == 0) part[((S_ - 2 + e) << 8) + b] = make_float2(px, py);
        }
    }
}

// out[r] = bd + sum_{f in chunk r} softmax(score)_f * d_f, chunk = 2048 flat
// (s,b) pairs with s in [8r,8r+8). ba is softmax-invariant -> omitted.
__global__ __launch_bounds__(256) void attn_kernel(
    const float2* __restrict__ part, const float* __restrict__ bd,
    float* __restrict__ out)
{
    const int r = blockIdx.x;
    const int t = threadIdx.x;
    float sc[8], dv[8];
    float mx = -1e30f;
#pragma unroll
    for (int u = 0; u < 8; ++u) {
        int f = (r << 11) + (u << 8) + t;
        float2 a = part[f];
        sc[u] = a.x;
        dv[u] = a.y;
        mx = fmaxf(mx, sc[u]);
    }
    __shared__ float redm[4], redz[4], redw[4];
#pragma unroll
    for (int off = 32; off > 0; off >>= 1) mx = fmaxf(mx, __shfl_xor(mx, off, 64));
    if ((t & 63) == 0) redm[t >> 6] = mx;
    __syncthreads();
    mx = fmaxf(fmaxf(redm[0], redm[1]), fmaxf(redm[2], redm[3]));
    float z = 0.f, wv = 0.f;
#pragma unroll
    for (int u = 0; u < 8; ++u) {
        float e = __expf(sc[u] - mx);
        z += e;
        wv += e * dv[u];
    }
#pragma unroll
    for (int off = 32; off > 0; off >>= 1) {
        z += __shfl_xor(z, off, 64);
        wv += __shfl_xor(wv, off, 64);
    }
    if ((t & 63) == 0) { redz[t >> 6] = z; redw[t >> 6] = wv; }
    __syncthreads();
    if (t == 0) {
        float Z = redz[0] + redz[1] + redz[2] + redz[3];
        float W = redw[0] + redw[1] + redw[2] + redw[3];
        out[r] = bd[0] + W / Z;
    }
}

extern "C" void kernel_launch(void* const* d_in, const int* in_sizes, int n_in,
                              void* d_out, int out_size, void* d_ws, size_t ws_size,
                              hipStream_t stream) {
    const float* x  = (const float*)d_in[0];
    const float* Wi = (const float*)d_in[1];
    const float* bi = (const float*)d_in[2];
    const float* Wh = (const float*)d_in[3];
    const float* bh = (const float*)d_in[4];
    const float* Wa = (const float*)d_in[5];
    // d_in[6] = ba: constant shift inside each softmax chunk -> no effect.
    const float* Wd = (const float*)d_in[7];
    const float* bd = (const float*)d_in[8];
    const int*  rdp = (const int*)d_in[9];

    // Workspace: one (S*B) float2 array of combined {score, d} (4 MiB)
    float2* part = (float2*)d_ws;

    rnn_kernel<<<B_, 512, 0, stream>>>(x, Wi, bi, Wh, bh, Wa, Wd, rdp, part);
    attn_kernel<<<B_, 256, 0, stream>>>(part, bd, (float*)d_out);
}